// Round 1
// baseline (534.752 us; speedup 1.0000x reference)
//
#include <hip/hip_runtime.h>

// Prop3D: x (8, 4, 512, 64) f32 -> (map_hidden, map_mask), each (8, 512, 4, 64, 65) f32.
// For rel in 0..3 (base b = 1<<rel):
//   valid (s,e): s%b==0, e<64, (e-s)%b==0, e-s>=b
//   hidden[bi,d,rel,s,e] = max(x[bi,rel,d, s .. s+k-1]), k=(e-s)/b   (window length k!)
//   mask  [..same..]     = 1.0
// Everything else is 0. Output is hidden ++ mask, flat.
//
// R1 change vs baseline: (a) plain stores instead of __builtin_nontemporal_store —
// the harness's own fillBuffer sustains 6.2 TB/s with cached stores while our nt
// stores ran at ~3.0 TB/s; (b) sparse table built by wave 0 via __shfl with a
// single __syncthreads instead of 6 barrier rounds.

#define HIDDEN_ELEMS 68157440LL   // 8*512*4*64*65

typedef float vfloat4 __attribute__((ext_vector_type(4)));

__global__ __launch_bounds__(256) void prop3d_kernel(const float* __restrict__ x,
                                                     float* __restrict__ out) {
    // gid = ((b*512)+d)*4 + rel  -> matches output (B, D, rel, ...) layout
    const int gid = blockIdx.x;          // 0..16383
    const int rel = gid & 3;
    const int d   = (gid >> 2) & 511;
    const int bi  = gid >> 11;           // batch 0..7
    const int t   = threadIdx.x;

    // Sparse table for O(1) range-max: ST[s][p] = max(x[s .. s+2^p-1]) (clamped; clamped
    // entries are never consumed by valid queries). Transposed [s][p] layout: lanes
    // sharing s with different p read consecutive banks.
    __shared__ float ST[64][6];

    // x[bi, rel, d, 0:64]
    const float* xr = x + (((long long)(bi * 4 + rel)) * 512 + d) * 64;

    // Wave 0 (threads 0..63) builds all 6 levels in-register via shuffles;
    // one barrier instead of six.
    if (t < 64) {
        float v = xr[t];
        ST[t][0] = v;
        #pragma unroll
        for (int p = 1; p < 6; ++p) {
            int j = t + (1 << (p - 1));
            j = j > 63 ? 63 : j;
            float o = __shfl(v, j, 64);   // lane j's level-(p-1) value
            v = fmaxf(v, o);
            ST[t][p] = v;
        }
    }
    __syncthreads();

    const int bmask = (1 << rel) - 1;

    // Per-block output region: 4160 floats (64 x 65) = 1040 float4, for each map.
    vfloat4* __restrict__ outH = reinterpret_cast<vfloat4*>(out) + (long long)gid * 1040;
    vfloat4* __restrict__ outM = reinterpret_cast<vfloat4*>(out + HIDDEN_ELEMS) + (long long)gid * 1040;

    for (int idx = t; idx < 1040; idx += 256) {
        const int f0 = idx * 4;
        vfloat4 v, mv;
        #pragma unroll
        for (int u = 0; u < 4; ++u) {
            const int f = f0 + u;          // 0..4159
            const int s = f / 65;          // magic-mul div
            const int e = f - s * 65;      // 0..64
            const int diff = e - s;
            const bool valid = (e < 64) & (diff > 0) &
                               ((s & bmask) == 0) & ((diff & bmask) == 0);
            const int k  = diff >> rel;        // window length when valid (>=1)
            const int kk = valid ? k : 1;      // clamp for safe LDS reads
            const int p  = 31 - __clz(kk);     // floor(log2(kk)), 0..5
            const float a = ST[s][p];
            const float c = ST[s + kk - (1 << p)][p];
            const float m = fmaxf(a, c);
            v[u]  = valid ? m : 0.0f;
            mv[u] = valid ? 1.0f : 0.0f;
        }
        outH[idx] = v;   // plain cached stores — match fillBuffer's 6.2 TB/s path
        outM[idx] = mv;
    }
}

extern "C" void kernel_launch(void* const* d_in, const int* in_sizes, int n_in,
                              void* d_out, int out_size, void* d_ws, size_t ws_size,
                              hipStream_t stream) {
    const float* x = (const float*)d_in[0];
    float* out = (float*)d_out;
    // 8 (B) * 512 (D) * 4 (rel) blocks
    prop3d_kernel<<<16384, 256, 0, stream>>>(x, out);
}

// Round 2
// 527.129 us; speedup vs baseline: 1.0145x; 1.0145x over previous
//
#include <hip/hip_runtime.h>

// Prop3D: x (8, 4, 512, 64) f32 -> (map_hidden, map_mask), each (8, 512, 4, 64, 65) f32.
// For rel in 0..3 (base b = 1<<rel):
//   valid (s,e): s%b==0, e<64, (e-s)%b==0, e-s>=b
//   hidden[bi,d,rel,s,e] = max(x[bi,rel,d, s .. s+k-1]), k=(e-s)/b   (window length k!)
//   mask  [..same..]     = 1.0
// Everything else is 0. Output is hidden ++ mask, flat.
//
// R2 change: split H and M into separate BLOCKS (even bid -> hidden, odd bid -> mask)
// so each wave writes exactly one pure store stream. Mask blocks read nothing, use no
// LDS, no barrier — structurally identical to the harness fill that sustains 6.2 TB/s.
// Probes the theory that the per-wave two-stream interleave capped us at 3.0 TB/s.

#define HIDDEN_ELEMS 68157440LL   // 8*512*4*64*65

typedef float vfloat4 __attribute__((ext_vector_type(4)));

__global__ __launch_bounds__(256) void prop3d_kernel(const float* __restrict__ x,
                                                     float* __restrict__ out) {
    const int t   = threadIdx.x;
    const int bid = blockIdx.x;            // 0..32767
    const int gid = bid >> 1;              // 0..16383 : ((b*512)+d)*4 + rel
    const int rel = gid & 3;
    const int bmask = (1 << rel) - 1;

    if (bid & 1) {
        // ---------------- mask-only block: pure pattern stream ----------------
        vfloat4* __restrict__ outM =
            reinterpret_cast<vfloat4*>(out + HIDDEN_ELEMS) + (long long)gid * 1040;
        for (int idx = t; idx < 1040; idx += 256) {
            const int f0 = idx * 4;
            vfloat4 mv;
            #pragma unroll
            for (int u = 0; u < 4; ++u) {
                const int f = f0 + u;          // 0..4159
                const int s = f / 65;
                const int e = f - s * 65;
                const int diff = e - s;
                const bool valid = (e < 64) & (diff > 0) &
                                   ((s & bmask) == 0) & ((diff & bmask) == 0);
                mv[u] = valid ? 1.0f : 0.0f;
            }
            outM[idx] = mv;
        }
        return;
    }

    // ---------------- hidden block: sparse-table range-max ----------------
    const int d  = (gid >> 2) & 511;
    const int bi = gid >> 11;

    // ST[s][p] = max(x[s .. s+2^p-1]) (clamped; clamped entries never consumed
    // by valid queries). [s][p] layout: lanes sharing s, differing p -> spread banks.
    __shared__ float ST[64][6];

    const float* xr = x + (((long long)(bi * 4 + rel)) * 512 + d) * 64;

    if (t < 64) {
        float v = xr[t];
        ST[t][0] = v;
        #pragma unroll
        for (int p = 1; p < 6; ++p) {
            int j = t + (1 << (p - 1));
            j = j > 63 ? 63 : j;
            float o = __shfl(v, j, 64);   // lane j's level-(p-1) value
            v = fmaxf(v, o);
            ST[t][p] = v;
        }
    }
    __syncthreads();

    vfloat4* __restrict__ outH = reinterpret_cast<vfloat4*>(out) + (long long)gid * 1040;

    for (int idx = t; idx < 1040; idx += 256) {
        const int f0 = idx * 4;
        vfloat4 v;
        #pragma unroll
        for (int u = 0; u < 4; ++u) {
            const int f = f0 + u;          // 0..4159
            const int s = f / 65;
            const int e = f - s * 65;
            const int diff = e - s;
            const bool valid = (e < 64) & (diff > 0) &
                               ((s & bmask) == 0) & ((diff & bmask) == 0);
            const int k  = diff >> rel;        // window length when valid (>=1)
            const int kk = valid ? k : 1;      // clamp for safe LDS reads
            const int p  = 31 - __clz(kk);     // floor(log2(kk)), 0..5
            const float a = ST[s][p];
            const float c = ST[s + kk - (1 << p)][p];
            const float m = fmaxf(a, c);
            v[u] = valid ? m : 0.0f;
        }
        outH[idx] = v;
    }
}

extern "C" void kernel_launch(void* const* d_in, const int* in_sizes, int n_in,
                              void* d_out, int out_size, void* d_ws, size_t ws_size,
                              hipStream_t stream) {
    const float* x = (const float*)d_in[0];
    float* out = (float*)d_out;
    // 2 x (8 B * 512 D * 4 rel) blocks: even -> hidden, odd -> mask
    prop3d_kernel<<<32768, 256, 0, stream>>>(x, out);
}